// Round 9
// baseline (4930.640 us; speedup 1.0000x reference)
//
#include <hip/hip_runtime.h>
#include <math.h>

// ESN: B=64, T=2048, I=25, R=512, O=50, alpha=0.5
// R9: 512 blocks x 512 threads, 8 blocks/batch: b=blk&63, g=blk>>6 owns rows
// [g*64,(g+1)*64). 2 blocks/CU (launch_bounds(512,4) caps VGPR at 128 ->
// guaranteed co-residency of all 512 blocks; different-batch blocks overlap
// each other's exchange latency).
// Thread tile: 1 row x 64 cols: row=tid>>3, chunk c=tid&7 covers cols
// [c*64,(c+1)*64). W slice row in 32 v2f (64 VGPR). Row reduce = 2 quad-perm
// DPP + ds_swizzle xor4. Win projection FOLDED into the same reduce (chunk c
// contributes x-terms k=c*4..c*4+3, k<25). Padded LDS idx(c)=c+4*(c>>6):
// matvec reads are 8-lane broadcasts (free), conflict-free.
// Seqlock protocol (R5/R8-proven): {h,tag=t+1} 8B pairs, parity double
// buffer, stores/loads sc0 sc1 (IC), single-asm load+waitcnt, skew<=1 by
// all-to-all mutual dependence. Waves 1..7 each fetch one remote slice.

typedef float v2f __attribute__((ext_vector_type(2)));
typedef float v4f __attribute__((ext_vector_type(4)));

template<int CTRL>
__device__ __forceinline__ float dpp_add(float x) {
    int y = __builtin_amdgcn_update_dpp(0, __float_as_int(x), CTRL, 0xF, 0xF, false);
    return x + __int_as_float(y);
}
// 0xB1 quad_perm[1,0,3,2], 0x4E quad_perm[2,3,0,1], 0x124 row_ror:4,
// 0x128 row_ror:8, 0x142 row_bcast15

__device__ __forceinline__ void store_ic8(float* p, float h, int tag) {
    v2f v; v[0] = h; v[1] = __int_as_float(tag);
    asm volatile("global_store_dwordx2 %0, %1, off sc0 sc1"
                 :: "v"(p), "v"(v) : "memory");
}
__device__ __forceinline__ v4f load_ic16(const float* p) {
    v4f r;
    asm volatile("global_load_dwordx4 %0, %1, off sc0 sc1\n\ts_waitcnt vmcnt(0)"
                 : "=&v"(r) : "v"(p) : "memory");
    return r;
}

// padded LDS index: +4 floats (16B) per 64-float chunk -> bank-conflict-free
__device__ __forceinline__ int pidx(int c) { return c + ((c >> 6) << 2); }

__global__ void __launch_bounds__(512, 4)
esn_kernel(const float* __restrict__ x, const float* __restrict__ Win,
           const float* __restrict__ W, const float* __restrict__ Wout,
           float* __restrict__ out, float* __restrict__ Hf)
{
    const int b    = blockIdx.x & 63;
    const int g    = blockIdx.x >> 6;      // 0..7
    const int tid  = threadIdx.x;
    const int row  = tid >> 3;             // 0..63 local row
    const int c    = tid & 7;              // chunk: cols [c*64,(c+1)*64)
    const int lane = tid & 63;
    const int wv   = tid >> 6;             // wave 0..7

    __shared__ __align__(16) float hperm[2][544];   // 512 + 8*4 pad

    // ---- W row-slice -> 32 v2f (64 VGPR)
    const int myrow = g*64 + row;
    v2f Wreg[32];
    {
        const float* wp = W + (size_t)myrow*512 + c*64;
        #pragma unroll
        for (int k = 0; k < 16; ++k) {
            v4f w = *(const v4f*)(wp + 4*k);
            Wreg[2*k]   = (v2f){w.x, w.y};
            Wreg[2*k+1] = (v2f){w.z, w.w};
        }
    }

    // ---- Win fragment: chunk c holds k = c*4..c*4+3 (k<25)
    float WinP[4];
    #pragma unroll
    for (int j = 0; j < 4; ++j) {
        const int k = c*4 + j;
        WinP[j] = (k < 25) ? Win[myrow*25 + k] : 0.f;
    }

    // ---- Wout fragment: block g owns outputs [o0, o0+ocnt), wave wv -> one
    const int o0   = g*6 + (g < 2 ? g : 2);
    const int ocnt = 6 + (g < 2 ? 1 : 0);
    const bool ovalid = (wv < ocnt);
    const int o = o0 + (ovalid ? wv : 0);
    float WoutR[8];
    #pragma unroll
    for (int j = 0; j < 8; ++j)
        WoutR[j] = ovalid ? Wout[o*512 + lane*8 + j] : 0.f;

    hperm[0][tid] = 0.f;
    if (tid < 32) hperm[0][512 + tid] = 0.f;
    float holdv = 0.f;

    const float* xrow = x   + (size_t)b * 2048 * 25;
    float*       orow = out + (size_t)b * 2048 * 50;
    float* HfB0 = Hf + (size_t)b * 1024;           // par-0 base (pairs)
    const int s = (g + wv) & 7;                     // slice wave wv fetches (wv>=1)

    // x fragment for t=0
    float xq[4];
    #pragma unroll
    for (int j = 0; j < 4; ++j) {
        const int k = c*4 + j;
        xq[j] = (k < 25) ? xrow[k] : 0.f;
    }

    __syncthreads();

    for (int t = 0; t < 2048; ++t) {
        const int par  = t & 1;
        const int npar = par ^ 1;
        const int want = t + 1;
        float* HfN = HfB0 + (size_t)npar * 64 * 1024;

        // ---- matvec: row dot over chunk c (8-lane-broadcast LDS reads)
        v2f acc = {0.f, 0.f};
        {
            const float* hp = &hperm[par][68*c];
            #pragma unroll
            for (int k = 0; k < 16; ++k) {
                v4f hv = *(const v4f*)(hp + 4*k);
                acc = __builtin_elementwise_fma(Wreg[2*k],   (v2f){hv.x, hv.y}, acc);
                acc = __builtin_elementwise_fma(Wreg[2*k+1], (v2f){hv.z, hv.w}, acc);
            }
        }
        float y = acc[0] + acc[1];
        #pragma unroll
        for (int j = 0; j < 4; ++j) y = fmaf(WinP[j], xq[j], y);   // fold u in

        // ---- 8-lane row reduce: 2 DPP + xor-4 swizzle
        y = dpp_add<0xB1>(y);
        y = dpp_add<0x4E>(y);
        y += __int_as_float(__builtin_amdgcn_ds_swizzle(__float_as_int(y), 0x101F));

        // ---- finalize + publish (chunk-0 lanes, 8 rows/wave)
        if (c == 0) {
            const float e  = __expf(2.f * y);
            const float th = 1.f - 2.f * __builtin_amdgcn_rcpf(e + 1.f);  // tanh
            holdv = 0.5f * holdv + 0.5f * th;
            hperm[npar][68*g + row] = holdv;             // own slice via LDS
            store_ic8(&HfN[myrow*2], holdv, want);
        }

        // ---- filler under store landing: x prefetch (t+1) + output proj
        {
            const int tt = (t < 2047) ? t + 1 : 2047;
            const float* xp = xrow + tt*25 + c*4;
            #pragma unroll
            for (int j = 0; j < 4; ++j)
                xq[j] = (c*4 + j < 25) ? xp[j] : 0.f;
        }
        if (ovalid) {
            const int lb = 8*lane + ((lane >> 3) << 2);
            v4f h0 = *(const v4f*)&hperm[par][lb];
            v4f h1 = *(const v4f*)&hperm[par][lb + 4];
            float opv;
            opv = WoutR[0]*h0.x;
            opv = fmaf(WoutR[1], h0.y, opv);
            opv = fmaf(WoutR[2], h0.z, opv);
            opv = fmaf(WoutR[3], h0.w, opv);
            opv = fmaf(WoutR[4], h1.x, opv);
            opv = fmaf(WoutR[5], h1.y, opv);
            opv = fmaf(WoutR[6], h1.z, opv);
            opv = fmaf(WoutR[7], h1.w, opv);
            opv = dpp_add<0xB1>(opv);  opv = dpp_add<0x4E>(opv);
            opv = dpp_add<0x124>(opv); opv = dpp_add<0x128>(opv);
            opv = dpp_add<0x142>(opv);
            const float lo = __shfl(opv, 31), hi = __shfl(opv, 63);
            if (t > 0 && lane == 0)
                orow[(size_t)(t-1)*50 + o] = lo + hi;
        }

        // ---- fetch waves 1..7: one remote 64-row slice each (seqlock retry)
        if (wv >= 1) {
            if (lane < 32) {
                const float* p = HfN + (s*128 + 4*lane);
                v4f d = load_ic16(p);
                while (__any((__float_as_int(d.y) != want) |
                             (__float_as_int(d.w) != want))) {
                    d = load_ic16(p);
                }
                *(v2f*)&hperm[npar][68*s + 2*lane] = (v2f){d.x, d.z};
            }
        }
        __syncthreads();   // the ONLY barrier per step
    }

    // epilogue: out[b][2047] from h_2048 (parity 0)
    if (ovalid) {
        const int lb = 8*lane + ((lane >> 3) << 2);
        v4f h0 = *(const v4f*)&hperm[0][lb];
        v4f h1 = *(const v4f*)&hperm[0][lb + 4];
        float opv;
        opv = WoutR[0]*h0.x;
        opv = fmaf(WoutR[1], h0.y, opv);
        opv = fmaf(WoutR[2], h0.z, opv);
        opv = fmaf(WoutR[3], h0.w, opv);
        opv = fmaf(WoutR[4], h1.x, opv);
        opv = fmaf(WoutR[5], h1.y, opv);
        opv = fmaf(WoutR[6], h1.z, opv);
        opv = fmaf(WoutR[7], h1.w, opv);
        opv = dpp_add<0xB1>(opv);  opv = dpp_add<0x4E>(opv);
        opv = dpp_add<0x124>(opv); opv = dpp_add<0x128>(opv);
        opv = dpp_add<0x142>(opv);
        const float lo = __shfl(opv, 31), hi = __shfl(opv, 63);
        if (lane == 0)
            orow[(size_t)2047*50 + o] = lo + hi;
    }
}

extern "C" void kernel_launch(void* const* d_in, const int* in_sizes, int n_in,
                              void* d_out, int out_size, void* d_ws, size_t ws_size,
                              hipStream_t stream)
{
    (void)in_sizes; (void)n_in; (void)out_size; (void)ws_size;
    const float* x    = (const float*)d_in[0];
    const float* Win  = (const float*)d_in[1];
    const float* W    = (const float*)d_in[2];
    const float* Wout = (const float*)d_in[3];
    float* out = (float*)d_out;
    float* Hf  = (float*)d_ws;   // [2][64][512] x {h,tag} = 512 KB
    esn_kernel<<<dim3(512), dim3(512), 0, stream>>>(x, Win, W, Wout, out, Hf);
}